// Round 11
// baseline (728.176 us; speedup 1.0000x reference)
//
#include <hip/hip_runtime.h>

#define NC 300000
#define NP 150000
#define NG 2000
#define NB 500
#define SCAN_B 1024
#define BK_SHIFT 11
#define BK_KEYS 2048   // keys per bucket
#define NBKT 513       // cdiv(RTOT, BK_KEYS)
#define CH 8192        // edges per chunk (bcount/msplit)

typedef unsigned int u32;
typedef float  f32x4 __attribute__((ext_vector_type(4)));
typedef unsigned int u32x4 __attribute__((ext_vector_type(4)));

static inline unsigned cdiv(long long a, long long b) { return (unsigned)((a + b - 1) / b); }

// ---------- bf16 helpers ----------
__device__ __forceinline__ float b2f(u32 h) {
    union { u32 u; float f; } c; c.u = h << 16; return c.f;
}
__device__ __forceinline__ u32 f2b(float f) {
    union { float f; u32 u; } c; c.f = f;
    return (c.u + 0x7FFFu + ((c.u >> 16) & 1u)) >> 16;   // RNE
}
__device__ __forceinline__ void unpack8(uint4 v, float* o) {
    o[0] = b2f(v.x & 0xFFFFu); o[1] = b2f(v.x >> 16);
    o[2] = b2f(v.y & 0xFFFFu); o[3] = b2f(v.y >> 16);
    o[4] = b2f(v.z & 0xFFFFu); o[5] = b2f(v.z >> 16);
    o[6] = b2f(v.w & 0xFFFFu); o[7] = b2f(v.w >> 16);
}
__device__ __forceinline__ void unpack8v(u32x4 v, float* o) {
    o[0] = b2f(v.x & 0xFFFFu); o[1] = b2f(v.x >> 16);
    o[2] = b2f(v.y & 0xFFFFu); o[3] = b2f(v.y >> 16);
    o[4] = b2f(v.z & 0xFFFFu); o[5] = b2f(v.z >> 16);
    o[6] = b2f(v.w & 0xFFFFu); o[7] = b2f(v.w >> 16);
}
__device__ __forceinline__ uint4 pack8(const float* a) {
    uint4 v;
    v.x = f2b(a[0]) | (f2b(a[1]) << 16);
    v.y = f2b(a[2]) | (f2b(a[3]) << 16);
    v.z = f2b(a[4]) | (f2b(a[5]) << 16);
    v.w = f2b(a[6]) | (f2b(a[7]) << 16);
    return v;
}

// ---------- fused f32->bf16 convert of all 4 tables (+ f32 copy for g/b outputs) ----------
__global__ void convert_all(const float* __restrict__ cw, const float* __restrict__ pw,
                            const float* __restrict__ gw, const float* __restrict__ bw,
                            uint4* __restrict__ c16, uint4* __restrict__ p16,
                            uint4* __restrict__ g16, uint4* __restrict__ b16,
                            float* __restrict__ outg, float* __restrict__ outb) {
    const int C8 = NC * 8, P8 = NP * 8, G8 = NG * 8, B8 = NB * 8;
    int i = blockIdx.x * blockDim.x + threadIdx.x;
    const float* in; uint4* out16; float* cpy = nullptr; int j;
    if (i < C8)                         { in = cw; out16 = c16; j = i; }
    else if ((j = i - C8) < P8)         { in = pw; out16 = p16; }
    else if ((j = i - C8 - P8) < G8)    { in = gw; out16 = g16; cpy = outg; }
    else if ((j = i - C8 - P8 - G8) < B8){ in = bw; out16 = b16; cpy = outb; }
    else return;
    const float4* p = (const float4*)(in + (size_t)j * 8);
    float4 a = p[0], b = p[1];
    float t[8] = { a.x, a.y, a.z, a.w, b.x, b.y, b.z, b.w };
    out16[j] = pack8(t);
    if (cpy) { float4* q = (float4*)(cpy + (size_t)j * 8); q[0] = a; q[1] = b; }
}

// ---------- fused CSR build over all 6 edge sets ----------
struct Edges6 {
    const int* src[6];
    const int* dst[6];
    int cum[7];      // cumulative edge-count offsets (cum[6] = total)
    int ctbase[7];   // base key of each set's segment (ctbase[6] = RTOT)
};

// ---------- stage A: bucket-granularity counts via LDS histogram ----------
__global__ void bcount(Edges6 e, int* __restrict__ gcount, int total) {
    __shared__ int hist[NBKT];
    int t = threadIdx.x;
    int j0 = blockIdx.x * CH;
    for (int b = t; b < NBKT; b += blockDim.x) hist[b] = 0;
    __syncthreads();
    #pragma unroll 4
    for (int q = 0; q < CH / 256; ++q) {
        int j = j0 + q * 256 + t;
        if (j < total) {
            int k = 0;
            #pragma unroll
            for (int qq = 1; qq < 6; ++qq) k += (j >= e.cum[qq]);
            int key = e.ctbase[k] + __builtin_nontemporal_load(e.src[k] + (j - e.cum[k]));
            atomicAdd(&hist[key >> BK_SHIFT], 1);
        }
    }
    __syncthreads();
    for (int b = t; b < NBKT; b += blockDim.x) {
        int c = hist[b];
        if (c > 0) atomicAdd(gcount + b, c);
    }
}

// ---------- stage B: one-block scan of 513 bucket counts -> gbase, gcur ----------
__global__ void bscan(const int* __restrict__ gcount, int* __restrict__ gbase,
                      int* __restrict__ gcur, int nb) {
    __shared__ int sm[SCAN_B];
    int t = threadIdx.x;
    int v = (t < nb) ? gcount[t] : 0;
    sm[t] = v; __syncthreads();
    for (int off = 1; off < SCAN_B; off <<= 1) {
        int add = (t >= off) ? sm[t - off] : 0;
        __syncthreads();
        sm[t] += add; __syncthreads();
    }
    int excl = sm[t] - v;
    if (t < nb) { gbase[t] = excl; gcur[t] = excl; }
    if (t == nb - 1) gbase[nb] = sm[t];
}

// ---------- stage C: 3-phase multisplit into buckets, dense stage writes ----------
// stage word = (key & 2047) << 19 | dst   (dst < 2^19)
__global__ void msplit(Edges6 e, int* __restrict__ gcur, u32* __restrict__ stage, int total) {
    __shared__ int hist[NBKT];
    __shared__ int bse[NBKT];
    int t = threadIdx.x;
    int j0 = blockIdx.x * CH;
    for (int b = t; b < NBKT; b += blockDim.x) hist[b] = 0;
    __syncthreads();
    #pragma unroll 4
    for (int q = 0; q < CH / 256; ++q) {
        int j = j0 + q * 256 + t;
        if (j < total) {
            int k = 0;
            #pragma unroll
            for (int qq = 1; qq < 6; ++qq) k += (j >= e.cum[qq]);
            int key = e.ctbase[k] + __builtin_nontemporal_load(e.src[k] + (j - e.cum[k]));
            atomicAdd(&hist[key >> BK_SHIFT], 1);
        }
    }
    __syncthreads();
    for (int b = t; b < NBKT; b += blockDim.x) {
        int c = hist[b];
        bse[b] = (c > 0) ? atomicAdd(gcur + b, c) : 0;
        hist[b] = 0;
    }
    __syncthreads();
    #pragma unroll 4
    for (int q = 0; q < CH / 256; ++q) {
        int j = j0 + q * 256 + t;
        if (j < total) {
            int k = 0;
            #pragma unroll
            for (int qq = 1; qq < 6; ++qq) k += (j >= e.cum[qq]);
            int jj = j - e.cum[k];
            int key = e.ctbase[k] + __builtin_nontemporal_load(e.src[k] + jj);
            int d = __builtin_nontemporal_load(e.dst[k] + jj);
            int b = key >> BK_SHIFT;
            int off = atomicAdd(&hist[b], 1);
            stage[bse[b] + off] = ((u32)(key & (BK_KEYS - 1)) << 19) | (u32)d;
        }
    }
}

// ---------- stage D: per-bucket LDS histogram+scan -> rowptr slice + place pm ----------
__global__ void sortb(const int* __restrict__ gbase, const u32* __restrict__ stage,
                      int* __restrict__ pm, int* __restrict__ rp, int rtot) {
    __shared__ int cur[BK_KEYS];
    __shared__ int part[512];
    int b = blockIdx.x, t = threadIdx.x;
    int k0 = b << BK_SHIFT;
    int base = gbase[b], end = gbase[b + 1];
    for (int q = t; q < BK_KEYS; q += 512) cur[q] = 0;
    __syncthreads();
    for (int i = base + t; i < end; i += 512)
        atomicAdd(&cur[stage[i] >> 19], 1);
    __syncthreads();
    int a0 = cur[4 * t], a1 = cur[4 * t + 1], a2 = cur[4 * t + 2], a3 = cur[4 * t + 3];
    int s = a0 + a1 + a2 + a3;
    part[t] = s; __syncthreads();
    for (int off = 1; off < 512; off <<= 1) {
        int add = (t >= off) ? part[t - off] : 0;
        __syncthreads();
        part[t] += add; __syncthreads();
    }
    int c0 = base + part[t] - s;
    int c1 = c0 + a0, c2 = c1 + a1, c3 = c2 + a2;
    cur[4 * t] = c0; cur[4 * t + 1] = c1; cur[4 * t + 2] = c2; cur[4 * t + 3] = c3;
    int ki = k0 + 4 * t;
    if (ki + 3 < rtot) {
        *(int4*)(rp + ki) = make_int4(c0, c1, c2, c3);
    } else {
        if (ki     < rtot) rp[ki]     = c0;
        if (ki + 1 < rtot) rp[ki + 1] = c1;
        if (ki + 2 < rtot) rp[ki + 2] = c2;
        if (ki + 3 < rtot) rp[ki + 3] = c3;
    }
    __syncthreads();
    for (int i = base + t; i < end; i += 512) {
        u32 w = stage[i];
        int off = atomicAdd(&cur[w >> 19], 1);
        pm[off] = (int)(w & 0x7FFFFu);
    }
}

// ---------- mean-agg of bf16 rows, f32 accumulate, 4-deep MLP, NT pm loads ----------
__device__ __forceinline__ void acc8(uint4 v, float* sum) {
    float t[8]; unpack8(v, t);
    #pragma unroll
    for (int k = 0; k < 8; ++k) sum[k] += t[k];
}
__device__ __forceinline__ void agg8se(int s, int e, const int* __restrict__ pm,
                                       const uint4* __restrict__ tgt,
                                       int lane, float w, float* acc) {
    float sum[8] = {0, 0, 0, 0, 0, 0, 0, 0};
    int i = s;
    for (; i + 4 <= e; i += 4) {
        int d0 = __builtin_nontemporal_load(pm + i);
        int d1 = __builtin_nontemporal_load(pm + i + 1);
        int d2 = __builtin_nontemporal_load(pm + i + 2);
        int d3 = __builtin_nontemporal_load(pm + i + 3);
        uint4 v0 = tgt[(size_t)d0 * 8 + lane];
        uint4 v1 = tgt[(size_t)d1 * 8 + lane];
        uint4 v2 = tgt[(size_t)d2 * 8 + lane];
        uint4 v3 = tgt[(size_t)d3 * 8 + lane];
        acc8(v0, sum); acc8(v1, sum); acc8(v2, sum); acc8(v3, sum);
    }
    for (; i < e; ++i) {
        int d = __builtin_nontemporal_load(pm + i);
        uint4 v = tgt[(size_t)d * 8 + lane];
        acc8(v, sum);
    }
    int deg = e - s;
    float sc = w / (float)(deg > 1 ? deg : 1);
    #pragma unroll
    for (int k = 0; k < 8; ++k) acc[k] += sum[k] * sc;
}

// ---------- fused layer ----------
// modes 0/1: write next-snapshot only (no d_out access).
// mode 2: out = 0.25*(s0_f32 + s1_bf16 + s2_bf16 + acc) -- deferred 4-snapshot mean.
__global__ void layer_kernel(
    const int* __restrict__ rp_purch, const int* __restrict__ rp_pby,
    const int* __restrict__ rp_sim,   const int* __restrict__ rp_cop,
    const int* __restrict__ rp_bel,   const int* __restrict__ rp_comp,
    const int* __restrict__ pm,
    const uint4* __restrict__ c16, const uint4* __restrict__ p16,
    const uint4* __restrict__ g16, const uint4* __restrict__ b16,
    uint4* __restrict__ c16n, uint4* __restrict__ p16n,
    const float* __restrict__ cw, const float* __restrict__ pw,
    const uint4* __restrict__ s1c, const uint4* __restrict__ s1p,
    float* __restrict__ outc, float* __restrict__ outp,
    int mode)
{
    int t = blockIdx.x * blockDim.x + threadIdx.x;
    int gid = t >> 3;
    int lane = t & 7;
    float acc[8];
    if (gid < NP) {
        int row = gid;
        size_t idx = (size_t)row * 8 + lane;
        int s0 = rp_pby[row],  e0 = rp_pby[row + 1];
        int s1 = rp_sim[row],  e1 = rp_sim[row + 1];
        int s2 = rp_cop[row],  e2 = rp_cop[row + 1];
        int s3 = rp_bel[row],  e3 = rp_bel[row + 1];
        int s4 = rp_comp[row], e4 = rp_comp[row + 1];
        float base[8]; unpack8(p16[idx], base);
        #pragma unroll
        for (int k = 0; k < 8; ++k) acc[k] = base[k];
        agg8se(s0, e0, pm, c16, lane, 1.0f, acc);
        agg8se(s1, e1, pm, p16, lane, 0.5f, acc);
        agg8se(s2, e2, pm, p16, lane, 0.3f, acc);
        agg8se(s3, e3, pm, g16, lane, 0.2f, acc);
        agg8se(s4, e4, pm, b16, lane, 0.2f, acc);
        if (mode != 2) {
            p16n[idx] = pack8(acc);
        } else {
            const f32x4* s0p = (const f32x4*)(pw + (size_t)row * 64 + lane * 8);
            f32x4 a0 = __builtin_nontemporal_load(s0p);
            f32x4 a1 = __builtin_nontemporal_load(s0p + 1);
            u32x4 s1v = __builtin_nontemporal_load((const u32x4*)&s1p[idx]);
            float sv[8]; unpack8v(s1v, sv);
            f32x4 o0, o1;
            o0.x = 0.25f * (a0.x + sv[0] + base[0] + acc[0]);
            o0.y = 0.25f * (a0.y + sv[1] + base[1] + acc[1]);
            o0.z = 0.25f * (a0.z + sv[2] + base[2] + acc[2]);
            o0.w = 0.25f * (a0.w + sv[3] + base[3] + acc[3]);
            o1.x = 0.25f * (a1.x + sv[4] + base[4] + acc[4]);
            o1.y = 0.25f * (a1.y + sv[5] + base[5] + acc[5]);
            o1.z = 0.25f * (a1.z + sv[6] + base[6] + acc[6]);
            o1.w = 0.25f * (a1.w + sv[7] + base[7] + acc[7]);
            f32x4* o = (f32x4*)(outp + (size_t)row * 64 + lane * 8);
            __builtin_nontemporal_store(o0, o);
            __builtin_nontemporal_store(o1, o + 1);
        }
    } else if (gid < NP + NC) {
        int row = gid - NP;
        size_t idx = (size_t)row * 8 + lane;
        int s0 = rp_purch[row], e0 = rp_purch[row + 1];
        #pragma unroll
        for (int k = 0; k < 8; ++k) acc[k] = 0.f;
        agg8se(s0, e0, pm, p16, lane, 1.0f, acc);
        if (mode != 2) {
            c16n[idx] = pack8(acc);
        } else {
            float base[8]; unpack8(c16[idx], base);                       // s2
            const f32x4* s0c = (const f32x4*)(cw + (size_t)row * 64 + lane * 8);
            f32x4 a0 = __builtin_nontemporal_load(s0c);
            f32x4 a1 = __builtin_nontemporal_load(s0c + 1);
            u32x4 s1v = __builtin_nontemporal_load((const u32x4*)&s1c[idx]);
            float sv[8]; unpack8v(s1v, sv);                               // s1
            f32x4 o0, o1;
            o0.x = 0.25f * (a0.x + sv[0] + base[0] + acc[0]);
            o0.y = 0.25f * (a0.y + sv[1] + base[1] + acc[1]);
            o0.z = 0.25f * (a0.z + sv[2] + base[2] + acc[2]);
            o0.w = 0.25f * (a0.w + sv[3] + base[3] + acc[3]);
            o1.x = 0.25f * (a1.x + sv[4] + base[4] + acc[4]);
            o1.y = 0.25f * (a1.y + sv[5] + base[5] + acc[5]);
            o1.z = 0.25f * (a1.z + sv[6] + base[6] + acc[6]);
            o1.w = 0.25f * (a1.w + sv[7] + base[7] + acc[7]);
            f32x4* o = (f32x4*)(outc + (size_t)row * 64 + lane * 8);
            __builtin_nontemporal_store(o0, o);
            __builtin_nontemporal_store(o1, o + 1);
        }
    }
}

extern "C" void kernel_launch(void* const* d_in, const int* in_sizes, int n_in,
                              void* d_out, int out_size, void* d_ws, size_t ws_size,
                              hipStream_t stream) {
    const float* cust_w  = (const float*)d_in[0];
    const float* prod_w  = (const float*)d_in[1];
    const float* group_w = (const float*)d_in[2];
    const float* brand_w = (const float*)d_in[3];

    const int n_purch = in_sizes[4];
    const int n_pby   = in_sizes[6];
    const int n_sim   = in_sizes[8];
    const int n_cop   = in_sizes[10];
    const int n_bel   = in_sizes[12];
    const int n_comp  = in_sizes[14];
    const int n_edges[6] = { n_purch, n_pby, n_sim, n_cop, n_bel, n_comp };

    const size_t CSZ = (size_t)NC * 64;
    const size_t PSZ = (size_t)NP * 64;

    // ---- workspace layout ----
    char* base = (char*)d_ws;
    uint4* c16A = (uint4*)base;                 base += (size_t)NC * 128;
    uint4* c16B = (uint4*)base;                 base += (size_t)NC * 128;
    uint4* p16A = (uint4*)base;                 base += (size_t)NP * 128;
    uint4* p16B = (uint4*)base;                 base += (size_t)NP * 128;
    uint4* g16  = (uint4*)base;                 base += (size_t)NG * 128;
    uint4* b16  = (uint4*)base;                 base += (size_t)NB * 128;

    const int RP_PURCH = NC + 1;
    const int RP_OTHER = NP + 1;
    const int RTOT = RP_PURCH + 5 * RP_OTHER;   // 1,050,006 (NBKT*2048 >= RTOT)

    int* rp_all = (int*)base;                   base += (size_t)RTOT * 4;
    long long tot_edges = 0;
    for (int k = 0; k < 6; ++k) tot_edges += n_edges[k];
    int* pm_all = (int*)base;                   base += tot_edges * 4;
    u32* stage  = (u32*)base;                   base += tot_edges * 4;
    int* gcount = (int*)base;                   base += (size_t)NBKT * 4;
    int* gbase  = (int*)base;                   base += (size_t)(NBKT + 1) * 4;
    int* gcur   = (int*)base;

    int* rp_purch = rp_all;
    int* rp_pby   = rp_purch + RP_PURCH;
    int* rp_sim   = rp_pby + RP_OTHER;
    int* rp_cop   = rp_sim + RP_OTHER;
    int* rp_bel   = rp_cop + RP_OTHER;
    int* rp_comp  = rp_bel + RP_OTHER;

    float* out_c = (float*)d_out;
    float* out_p = out_c + CSZ;
    float* out_g = out_p + PSZ;
    float* out_b = out_g + (size_t)NG * 64;

    const int BT = 256;

    // ---- fused convert (also copies group/brand f32 outputs) ----
    const long long CVT = (long long)(NC + NP + NG + NB) * 8;
    convert_all<<<cdiv(CVT, BT), BT, 0, stream>>>(
        cust_w, prod_w, group_w, brand_w, c16A, p16A, g16, b16, out_g, out_b);

    // ---- CSR build: bucket-count -> bucket-scan -> multisplit -> bucket sort ----
    Edges6 E;
    E.src[0] = (const int*)d_in[4];  E.dst[0] = (const int*)d_in[5];
    E.src[1] = (const int*)d_in[6];  E.dst[1] = (const int*)d_in[7];
    E.src[2] = (const int*)d_in[8];  E.dst[2] = (const int*)d_in[9];
    E.src[3] = (const int*)d_in[10]; E.dst[3] = (const int*)d_in[11];
    E.src[4] = (const int*)d_in[12]; E.dst[4] = (const int*)d_in[13];
    E.src[5] = (const int*)d_in[14]; E.dst[5] = (const int*)d_in[15];
    E.cum[0] = 0;
    for (int k = 0; k < 6; ++k) E.cum[k + 1] = E.cum[k] + n_edges[k];
    E.ctbase[0] = 0;
    E.ctbase[1] = RP_PURCH;
    for (int k = 2; k < 6; ++k) E.ctbase[k] = E.ctbase[k - 1] + RP_OTHER;
    E.ctbase[6] = RTOT;
    const int TOT = E.cum[6];

    hipMemsetAsync(gcount, 0, (size_t)NBKT * 4, stream);
    bcount<<<cdiv(TOT, CH), BT, 0, stream>>>(E, gcount, TOT);
    bscan<<<1, SCAN_B, 0, stream>>>(gcount, gbase, gcur, NBKT);
    msplit<<<cdiv(TOT, CH), BT, 0, stream>>>(E, gcur, stage, TOT);
    sortb<<<NBKT, 512, 0, stream>>>(gbase, stage, pm_all, rp_all, RTOT);

    // ---- 3 fused layers; d_out written only by layer 2 (deferred mean) ----
    const long long LTHREADS = (long long)(NP + NC) * 8;
    layer_kernel<<<cdiv(LTHREADS, BT), BT, 0, stream>>>(
        rp_purch, rp_pby, rp_sim, rp_cop, rp_bel, rp_comp, pm_all,
        c16A, p16A, g16, b16, c16B, p16B,
        cust_w, prod_w, c16B, p16B, out_c, out_p, 0);
    layer_kernel<<<cdiv(LTHREADS, BT), BT, 0, stream>>>(
        rp_purch, rp_pby, rp_sim, rp_cop, rp_bel, rp_comp, pm_all,
        c16B, p16B, g16, b16, c16A, p16A,
        cust_w, prod_w, c16B, p16B, out_c, out_p, 1);
    layer_kernel<<<cdiv(LTHREADS, BT), BT, 0, stream>>>(
        rp_purch, rp_pby, rp_sim, rp_cop, rp_bel, rp_comp, pm_all,
        c16A, p16A, g16, b16, c16B, p16B,           // s2 = A (gather source)
        cust_w, prod_w, c16B, p16B,                 // s0 = inputs, s1 = B
        out_c, out_p, 2);
}

// Round 12
// 670.658 us; speedup vs baseline: 1.0858x; 1.0858x over previous
//
#include <hip/hip_runtime.h>

#define NC 300000
#define NP 150000
#define NG 2000
#define NB 500
#define SCAN_B 1024
#define BK_SHIFT 11
#define BK_KEYS 2048   // keys per bucket
#define NBKT 513       // cdiv(RTOT, BK_KEYS)
#define CH 8192        // edges per chunk (bcount/msplit)
#define ROWS (NP + NC) // 450,000 unified rows (product first)
#define RCH 4096       // rows per block in row-sort kernels

typedef unsigned int u32;
typedef float  f32x4 __attribute__((ext_vector_type(4)));
typedef unsigned int u32x4 __attribute__((ext_vector_type(4)));

static inline unsigned cdiv(long long a, long long b) { return (unsigned)((a + b - 1) / b); }

// ---------- bf16 helpers ----------
__device__ __forceinline__ float b2f(u32 h) {
    union { u32 u; float f; } c; c.u = h << 16; return c.f;
}
__device__ __forceinline__ u32 f2b(float f) {
    union { float f; u32 u; } c; c.f = f;
    return (c.u + 0x7FFFu + ((c.u >> 16) & 1u)) >> 16;   // RNE
}
__device__ __forceinline__ void unpack8(uint4 v, float* o) {
    o[0] = b2f(v.x & 0xFFFFu); o[1] = b2f(v.x >> 16);
    o[2] = b2f(v.y & 0xFFFFu); o[3] = b2f(v.y >> 16);
    o[4] = b2f(v.z & 0xFFFFu); o[5] = b2f(v.z >> 16);
    o[6] = b2f(v.w & 0xFFFFu); o[7] = b2f(v.w >> 16);
}
__device__ __forceinline__ void unpack8v(u32x4 v, float* o) {
    o[0] = b2f(v.x & 0xFFFFu); o[1] = b2f(v.x >> 16);
    o[2] = b2f(v.y & 0xFFFFu); o[3] = b2f(v.y >> 16);
    o[4] = b2f(v.z & 0xFFFFu); o[5] = b2f(v.z >> 16);
    o[6] = b2f(v.w & 0xFFFFu); o[7] = b2f(v.w >> 16);
}
__device__ __forceinline__ uint4 pack8(const float* a) {
    uint4 v;
    v.x = f2b(a[0]) | (f2b(a[1]) << 16);
    v.y = f2b(a[2]) | (f2b(a[3]) << 16);
    v.z = f2b(a[4]) | (f2b(a[5]) << 16);
    v.w = f2b(a[6]) | (f2b(a[7]) << 16);
    return v;
}

// ---------- fused f32->bf16 convert of all 4 tables (+ f32 copy for g/b outputs) ----------
__global__ void convert_all(const float* __restrict__ cw, const float* __restrict__ pw,
                            const float* __restrict__ gw, const float* __restrict__ bw,
                            uint4* __restrict__ c16, uint4* __restrict__ p16,
                            uint4* __restrict__ g16, uint4* __restrict__ b16,
                            float* __restrict__ outg, float* __restrict__ outb) {
    const int C8 = NC * 8, P8 = NP * 8, G8 = NG * 8, B8 = NB * 8;
    int i = blockIdx.x * blockDim.x + threadIdx.x;
    const float* in; uint4* out16; float* cpy = nullptr; int j;
    if (i < C8)                         { in = cw; out16 = c16; j = i; }
    else if ((j = i - C8) < P8)         { in = pw; out16 = p16; }
    else if ((j = i - C8 - P8) < G8)    { in = gw; out16 = g16; cpy = outg; }
    else if ((j = i - C8 - P8 - G8) < B8){ in = bw; out16 = b16; cpy = outb; }
    else return;
    const float4* p = (const float4*)(in + (size_t)j * 8);
    float4 a = p[0], b = p[1];
    float t[8] = { a.x, a.y, a.z, a.w, b.x, b.y, b.z, b.w };
    out16[j] = pack8(t);
    if (cpy) { float4* q = (float4*)(cpy + (size_t)j * 8); q[0] = a; q[1] = b; }
}

// ---------- fused CSR build over all 6 edge sets ----------
struct Edges6 {
    const int* src[6];
    const int* dst[6];
    int cum[7];      // cumulative edge-count offsets (cum[6] = total)
    int ctbase[7];   // base key of each set's segment (ctbase[6] = RTOT)
};

// ---------- stage A: bucket-granularity counts via LDS histogram ----------
__global__ void bcount(Edges6 e, int* __restrict__ gcount, int total) {
    __shared__ int hist[NBKT];
    int t = threadIdx.x;
    int j0 = blockIdx.x * CH;
    for (int b = t; b < NBKT; b += blockDim.x) hist[b] = 0;
    __syncthreads();
    #pragma unroll 4
    for (int q = 0; q < CH / 256; ++q) {
        int j = j0 + q * 256 + t;
        if (j < total) {
            int k = 0;
            #pragma unroll
            for (int qq = 1; qq < 6; ++qq) k += (j >= e.cum[qq]);
            int key = e.ctbase[k] + __builtin_nontemporal_load(e.src[k] + (j - e.cum[k]));
            atomicAdd(&hist[key >> BK_SHIFT], 1);
        }
    }
    __syncthreads();
    for (int b = t; b < NBKT; b += blockDim.x) {
        int c = hist[b];
        if (c > 0) atomicAdd(gcount + b, c);
    }
}

// ---------- stage B: one-block scan of 513 bucket counts -> gbase, gcur ----------
__global__ void bscan(const int* __restrict__ gcount, int* __restrict__ gbase,
                      int* __restrict__ gcur, int nb) {
    __shared__ int sm[SCAN_B];
    int t = threadIdx.x;
    int v = (t < nb) ? gcount[t] : 0;
    sm[t] = v; __syncthreads();
    for (int off = 1; off < SCAN_B; off <<= 1) {
        int add = (t >= off) ? sm[t - off] : 0;
        __syncthreads();
        sm[t] += add; __syncthreads();
    }
    int excl = sm[t] - v;
    if (t < nb) { gbase[t] = excl; gcur[t] = excl; }
    if (t == nb - 1) gbase[nb] = sm[t];
}

// ---------- stage C: 3-phase multisplit into buckets, dense stage writes ----------
// stage word = (key & 2047) << 19 | dst   (dst < 2^19)
__global__ void msplit(Edges6 e, int* __restrict__ gcur, u32* __restrict__ stage, int total) {
    __shared__ int hist[NBKT];
    __shared__ int bse[NBKT];
    int t = threadIdx.x;
    int j0 = blockIdx.x * CH;
    for (int b = t; b < NBKT; b += blockDim.x) hist[b] = 0;
    __syncthreads();
    #pragma unroll 4
    for (int q = 0; q < CH / 256; ++q) {
        int j = j0 + q * 256 + t;
        if (j < total) {
            int k = 0;
            #pragma unroll
            for (int qq = 1; qq < 6; ++qq) k += (j >= e.cum[qq]);
            int key = e.ctbase[k] + __builtin_nontemporal_load(e.src[k] + (j - e.cum[k]));
            atomicAdd(&hist[key >> BK_SHIFT], 1);
        }
    }
    __syncthreads();
    for (int b = t; b < NBKT; b += blockDim.x) {
        int c = hist[b];
        bse[b] = (c > 0) ? atomicAdd(gcur + b, c) : 0;
        hist[b] = 0;
    }
    __syncthreads();
    #pragma unroll 4
    for (int q = 0; q < CH / 256; ++q) {
        int j = j0 + q * 256 + t;
        if (j < total) {
            int k = 0;
            #pragma unroll
            for (int qq = 1; qq < 6; ++qq) k += (j >= e.cum[qq]);
            int jj = j - e.cum[k];
            int key = e.ctbase[k] + __builtin_nontemporal_load(e.src[k] + jj);
            int d = __builtin_nontemporal_load(e.dst[k] + jj);
            int b = key >> BK_SHIFT;
            int off = atomicAdd(&hist[b], 1);
            stage[bse[b] + off] = ((u32)(key & (BK_KEYS - 1)) << 19) | (u32)d;
        }
    }
}

// ---------- stage D: per-bucket LDS histogram+scan -> rowptr slice + place pm ----------
__global__ void sortb(const int* __restrict__ gbase, const u32* __restrict__ stage,
                      int* __restrict__ pm, int* __restrict__ rp, int rtot) {
    __shared__ int cur[BK_KEYS];
    __shared__ int part[512];
    int b = blockIdx.x, t = threadIdx.x;
    int k0 = b << BK_SHIFT;
    int base = gbase[b], end = gbase[b + 1];
    for (int q = t; q < BK_KEYS; q += 512) cur[q] = 0;
    __syncthreads();
    for (int i = base + t; i < end; i += 512)
        atomicAdd(&cur[stage[i] >> 19], 1);
    __syncthreads();
    int a0 = cur[4 * t], a1 = cur[4 * t + 1], a2 = cur[4 * t + 2], a3 = cur[4 * t + 3];
    int s = a0 + a1 + a2 + a3;
    part[t] = s; __syncthreads();
    for (int off = 1; off < 512; off <<= 1) {
        int add = (t >= off) ? part[t - off] : 0;
        __syncthreads();
        part[t] += add; __syncthreads();
    }
    int c0 = base + part[t] - s;
    int c1 = c0 + a0, c2 = c1 + a1, c3 = c2 + a2;
    cur[4 * t] = c0; cur[4 * t + 1] = c1; cur[4 * t + 2] = c2; cur[4 * t + 3] = c3;
    int ki = k0 + 4 * t;
    if (ki + 3 < rtot) {
        *(int4*)(rp + ki) = make_int4(c0, c1, c2, c3);
    } else {
        if (ki     < rtot) rp[ki]     = c0;
        if (ki + 1 < rtot) rp[ki + 1] = c1;
        if (ki + 2 < rtot) rp[ki + 2] = c2;
        if (ki + 3 < rtot) rp[ki + 3] = c3;
    }
    __syncthreads();
    for (int i = base + t; i < end; i += 512) {
        u32 w = stage[i];
        int off = atomicAdd(&cur[w >> 19], 1);
        pm[off] = (int)(w & 0x7FFFFu);
    }
}

// ---------- row workload bin: product rows 0..127, customer rows 128..255 ----------
__device__ __forceinline__ int row_bin(const int* __restrict__ rp, int gid) {
    if (gid < NP) {
        int td = 0;
        #pragma unroll
        for (int k = 0; k < 5; ++k) {
            int o = (NC + 1) + k * (NP + 1) + gid;
            td += rp[o + 1] - rp[o];
        }
        return td < 127 ? td : 127;
    } else {
        int r = gid - NP;
        int d = rp[r + 1] - rp[r];
        return 128 + (d < 127 ? d : 127);
    }
}

__global__ void rowhist(const int* __restrict__ rp, int* __restrict__ gbinc, int rows) {
    __shared__ int hist[256];
    int t = threadIdx.x;
    hist[t] = 0;
    __syncthreads();
    int j0 = blockIdx.x * RCH;
    for (int q = 0; q < RCH / 256; ++q) {
        int j = j0 + q * 256 + t;
        if (j < rows) atomicAdd(&hist[row_bin(rp, j)], 1);
    }
    __syncthreads();
    int c = hist[t];
    if (c > 0) atomicAdd(gbinc + t, c);
}

__global__ void rowscan(const int* __restrict__ gbinc, int* __restrict__ gcur256) {
    __shared__ int sm[256];
    int t = threadIdx.x;
    int v = gbinc[t];
    sm[t] = v; __syncthreads();
    for (int off = 1; off < 256; off <<= 1) {
        int add = (t >= off) ? sm[t - off] : 0;
        __syncthreads();
        sm[t] += add; __syncthreads();
    }
    gcur256[t] = sm[t] - v;
}

__global__ void rowplace(const int* __restrict__ rp, int* __restrict__ gcur256,
                         int* __restrict__ perm, int rows) {
    __shared__ int hist[256];
    __shared__ int bse[256];
    int t = threadIdx.x;
    hist[t] = 0;
    __syncthreads();
    int j0 = blockIdx.x * RCH;
    for (int q = 0; q < RCH / 256; ++q) {
        int j = j0 + q * 256 + t;
        if (j < rows) atomicAdd(&hist[row_bin(rp, j)], 1);
    }
    __syncthreads();
    int c = hist[t];
    bse[t] = (c > 0) ? atomicAdd(gcur256 + t, c) : 0;
    hist[t] = 0;
    __syncthreads();
    for (int q = 0; q < RCH / 256; ++q) {
        int j = j0 + q * 256 + t;
        if (j < rows) {
            int b = row_bin(rp, j);
            int off = atomicAdd(&hist[b], 1);
            perm[bse[b] + off] = j;
        }
    }
}

// materialize permuted segment bounds (sequential reads in layer kernel)
__global__ void permrp(const int* __restrict__ rp, const int* __restrict__ perm,
                       int4* __restrict__ pA, int4* __restrict__ pB, int2* __restrict__ pC,
                       int2* __restrict__ cinfo, int rows) {
    int j = blockIdx.x * blockDim.x + threadIdx.x;
    if (j >= rows) return;
    int pg = perm[j];
    if (pg < NP) {
        const int* r0 = rp + (NC + 1) + pg;               // pby
        const int* r1 = r0 + (NP + 1);                    // sim
        const int* r2 = r1 + (NP + 1);                    // cop
        const int* r3 = r2 + (NP + 1);                    // bel
        const int* r4 = r3 + (NP + 1);                    // comp
        pA[j] = make_int4(r0[0], r0[1], r1[0], r1[1]);
        pB[j] = make_int4(r2[0], r2[1], r3[0], r3[1]);
        pC[j] = make_int2(r4[0], r4[1]);
    } else {
        int r = pg - NP;
        cinfo[j - NP] = make_int2(rp[r], rp[r + 1]);
    }
}

// ---------- mean-agg of bf16 rows, f32 accumulate, 4-deep MLP (cached pm) ----------
__device__ __forceinline__ void acc8(uint4 v, float* sum) {
    float t[8]; unpack8(v, t);
    #pragma unroll
    for (int k = 0; k < 8; ++k) sum[k] += t[k];
}
__device__ __forceinline__ void agg8se(int s, int e, const int* __restrict__ pm,
                                       const uint4* __restrict__ tgt,
                                       int lane, float w, float* acc) {
    float sum[8] = {0, 0, 0, 0, 0, 0, 0, 0};
    int i = s;
    for (; i + 4 <= e; i += 4) {
        int d0 = pm[i], d1 = pm[i + 1], d2 = pm[i + 2], d3 = pm[i + 3];
        uint4 v0 = tgt[(size_t)d0 * 8 + lane];
        uint4 v1 = tgt[(size_t)d1 * 8 + lane];
        uint4 v2 = tgt[(size_t)d2 * 8 + lane];
        uint4 v3 = tgt[(size_t)d3 * 8 + lane];
        acc8(v0, sum); acc8(v1, sum); acc8(v2, sum); acc8(v3, sum);
    }
    for (; i < e; ++i) {
        uint4 v = tgt[(size_t)pm[i] * 8 + lane];
        acc8(v, sum);
    }
    int deg = e - s;
    float sc = w / (float)(deg > 1 ? deg : 1);
    #pragma unroll
    for (int k = 0; k < 8; ++k) acc[k] += sum[k] * sc;
}

// ---------- fused layer (degree-balanced rows via perm) ----------
// modes 0/1: write next-snapshot only. mode 2: out = 0.25*(s0+s1+s2+acc).
__global__ void layer_kernel(
    const int* __restrict__ perm,
    const int4* __restrict__ pA, const int4* __restrict__ pB, const int2* __restrict__ pC,
    const int2* __restrict__ cinfo,
    const int* __restrict__ pm,
    const uint4* __restrict__ c16, const uint4* __restrict__ p16,
    const uint4* __restrict__ g16, const uint4* __restrict__ b16,
    uint4* __restrict__ c16n, uint4* __restrict__ p16n,
    const float* __restrict__ cw, const float* __restrict__ pw,
    const uint4* __restrict__ s1c, const uint4* __restrict__ s1p,
    float* __restrict__ outc, float* __restrict__ outp,
    int mode)
{
    int t = blockIdx.x * blockDim.x + threadIdx.x;
    int gid = t >> 3;
    int lane = t & 7;
    float acc[8];
    if (gid < NP) {
        int row = perm[gid];                      // original product row
        size_t idx = (size_t)row * 8 + lane;
        int4 ia = pA[gid];
        int4 ib = pB[gid];
        int2 ic = pC[gid];
        float base[8]; unpack8(p16[idx], base);
        #pragma unroll
        for (int k = 0; k < 8; ++k) acc[k] = base[k];
        agg8se(ia.x, ia.y, pm, c16, lane, 1.0f, acc);   // pby
        agg8se(ia.z, ia.w, pm, p16, lane, 0.5f, acc);   // sim
        agg8se(ib.x, ib.y, pm, p16, lane, 0.3f, acc);   // cop
        agg8se(ib.z, ib.w, pm, g16, lane, 0.2f, acc);   // bel
        agg8se(ic.x, ic.y, pm, b16, lane, 0.2f, acc);   // comp
        if (mode != 2) {
            p16n[idx] = pack8(acc);
        } else {
            const f32x4* s0p = (const f32x4*)(pw + (size_t)row * 64 + lane * 8);
            f32x4 a0 = __builtin_nontemporal_load(s0p);
            f32x4 a1 = __builtin_nontemporal_load(s0p + 1);
            u32x4 s1v = __builtin_nontemporal_load((const u32x4*)&s1p[idx]);
            float sv[8]; unpack8v(s1v, sv);
            f32x4 o0, o1;
            o0.x = 0.25f * (a0.x + sv[0] + base[0] + acc[0]);
            o0.y = 0.25f * (a0.y + sv[1] + base[1] + acc[1]);
            o0.z = 0.25f * (a0.z + sv[2] + base[2] + acc[2]);
            o0.w = 0.25f * (a0.w + sv[3] + base[3] + acc[3]);
            o1.x = 0.25f * (a1.x + sv[4] + base[4] + acc[4]);
            o1.y = 0.25f * (a1.y + sv[5] + base[5] + acc[5]);
            o1.z = 0.25f * (a1.z + sv[6] + base[6] + acc[6]);
            o1.w = 0.25f * (a1.w + sv[7] + base[7] + acc[7]);
            f32x4* o = (f32x4*)(outp + (size_t)row * 64 + lane * 8);
            __builtin_nontemporal_store(o0, o);
            __builtin_nontemporal_store(o1, o + 1);
        }
    } else if (gid < ROWS) {
        int row = perm[gid] - NP;                 // original customer row
        size_t idx = (size_t)row * 8 + lane;
        int2 se = cinfo[gid - NP];
        #pragma unroll
        for (int k = 0; k < 8; ++k) acc[k] = 0.f;
        agg8se(se.x, se.y, pm, p16, lane, 1.0f, acc);
        if (mode != 2) {
            c16n[idx] = pack8(acc);
        } else {
            float base[8]; unpack8(c16[idx], base);                       // s2
            const f32x4* s0c = (const f32x4*)(cw + (size_t)row * 64 + lane * 8);
            f32x4 a0 = __builtin_nontemporal_load(s0c);
            f32x4 a1 = __builtin_nontemporal_load(s0c + 1);
            u32x4 s1v = __builtin_nontemporal_load((const u32x4*)&s1c[idx]);
            float sv[8]; unpack8v(s1v, sv);                               // s1
            f32x4 o0, o1;
            o0.x = 0.25f * (a0.x + sv[0] + base[0] + acc[0]);
            o0.y = 0.25f * (a0.y + sv[1] + base[1] + acc[1]);
            o0.z = 0.25f * (a0.z + sv[2] + base[2] + acc[2]);
            o0.w = 0.25f * (a0.w + sv[3] + base[3] + acc[3]);
            o1.x = 0.25f * (a1.x + sv[4] + base[4] + acc[4]);
            o1.y = 0.25f * (a1.y + sv[5] + base[5] + acc[5]);
            o1.z = 0.25f * (a1.z + sv[6] + base[6] + acc[6]);
            o1.w = 0.25f * (a1.w + sv[7] + base[7] + acc[7]);
            f32x4* o = (f32x4*)(outc + (size_t)row * 64 + lane * 8);
            __builtin_nontemporal_store(o0, o);
            __builtin_nontemporal_store(o1, o + 1);
        }
    }
}

extern "C" void kernel_launch(void* const* d_in, const int* in_sizes, int n_in,
                              void* d_out, int out_size, void* d_ws, size_t ws_size,
                              hipStream_t stream) {
    const float* cust_w  = (const float*)d_in[0];
    const float* prod_w  = (const float*)d_in[1];
    const float* group_w = (const float*)d_in[2];
    const float* brand_w = (const float*)d_in[3];

    const int n_purch = in_sizes[4];
    const int n_pby   = in_sizes[6];
    const int n_sim   = in_sizes[8];
    const int n_cop   = in_sizes[10];
    const int n_bel   = in_sizes[12];
    const int n_comp  = in_sizes[14];
    const int n_edges[6] = { n_purch, n_pby, n_sim, n_cop, n_bel, n_comp };

    const size_t CSZ = (size_t)NC * 64;
    const size_t PSZ = (size_t)NP * 64;

    // ---- workspace layout ----
    char* base = (char*)d_ws;
    uint4* c16A = (uint4*)base;                 base += (size_t)NC * 128;
    uint4* c16B = (uint4*)base;                 base += (size_t)NC * 128;
    uint4* p16A = (uint4*)base;                 base += (size_t)NP * 128;
    uint4* p16B = (uint4*)base;                 base += (size_t)NP * 128;
    uint4* g16  = (uint4*)base;                 base += (size_t)NG * 128;
    uint4* b16  = (uint4*)base;                 base += (size_t)NB * 128;

    const int RP_PURCH = NC + 1;
    const int RP_OTHER = NP + 1;
    const int RTOT = RP_PURCH + 5 * RP_OTHER;   // 1,050,006 (NBKT*2048 >= RTOT)

    int* rp_all = (int*)base;                   base += (size_t)RTOT * 4;
    long long tot_edges = 0;
    for (int k = 0; k < 6; ++k) tot_edges += n_edges[k];
    int* pm_all = (int*)base;                   base += tot_edges * 4;
    u32* stage  = (u32*)base;                   base += tot_edges * 4;
    int* gcount = (int*)base;                   base += (size_t)NBKT * 4;
    int* gbase  = (int*)base;                   base += (size_t)(NBKT + 1) * 4;
    int* gcur   = (int*)base;                   base += (size_t)NBKT * 4;
    int* gbinc  = (int*)base;                   base += 256 * 4;
    int* gcur256= (int*)base;                   base += 256 * 4;
    int* perm   = (int*)base;                   base += (size_t)ROWS * 4;
    int4* pA    = (int4*)base;                  base += (size_t)NP * 16;
    int4* pB    = (int4*)base;                  base += (size_t)NP * 16;
    int2* pC    = (int2*)base;                  base += (size_t)NP * 8;
    int2* cinfo = (int2*)base;                  base += (size_t)NC * 8;

    float* out_c = (float*)d_out;
    float* out_p = out_c + CSZ;
    float* out_g = out_p + PSZ;
    float* out_b = out_g + (size_t)NG * 64;

    const int BT = 256;

    // ---- fused convert (also copies group/brand f32 outputs) ----
    const long long CVT = (long long)(NC + NP + NG + NB) * 8;
    convert_all<<<cdiv(CVT, BT), BT, 0, stream>>>(
        cust_w, prod_w, group_w, brand_w, c16A, p16A, g16, b16, out_g, out_b);

    // ---- CSR build: bucket-count -> bucket-scan -> multisplit -> bucket sort ----
    Edges6 E;
    E.src[0] = (const int*)d_in[4];  E.dst[0] = (const int*)d_in[5];
    E.src[1] = (const int*)d_in[6];  E.dst[1] = (const int*)d_in[7];
    E.src[2] = (const int*)d_in[8];  E.dst[2] = (const int*)d_in[9];
    E.src[3] = (const int*)d_in[10]; E.dst[3] = (const int*)d_in[11];
    E.src[4] = (const int*)d_in[12]; E.dst[4] = (const int*)d_in[13];
    E.src[5] = (const int*)d_in[14]; E.dst[5] = (const int*)d_in[15];
    E.cum[0] = 0;
    for (int k = 0; k < 6; ++k) E.cum[k + 1] = E.cum[k] + n_edges[k];
    E.ctbase[0] = 0;
    E.ctbase[1] = RP_PURCH;
    for (int k = 2; k < 6; ++k) E.ctbase[k] = E.ctbase[k - 1] + RP_OTHER;
    E.ctbase[6] = RTOT;
    const int TOT = E.cum[6];

    hipMemsetAsync(gcount, 0, (size_t)NBKT * 4, stream);
    hipMemsetAsync(gbinc, 0, 256 * 4, stream);
    bcount<<<cdiv(TOT, CH), BT, 0, stream>>>(E, gcount, TOT);
    bscan<<<1, SCAN_B, 0, stream>>>(gcount, gbase, gcur, NBKT);
    msplit<<<cdiv(TOT, CH), BT, 0, stream>>>(E, gcur, stage, TOT);
    sortb<<<NBKT, 512, 0, stream>>>(gbase, stage, pm_all, rp_all, RTOT);

    // ---- degree-balanced row permutation ----
    rowhist<<<cdiv(ROWS, RCH), 256, 0, stream>>>(rp_all, gbinc, ROWS);
    rowscan<<<1, 256, 0, stream>>>(gbinc, gcur256);
    rowplace<<<cdiv(ROWS, RCH), 256, 0, stream>>>(rp_all, gcur256, perm, ROWS);
    permrp<<<cdiv(ROWS, BT), BT, 0, stream>>>(rp_all, perm, pA, pB, pC, cinfo, ROWS);

    // ---- 3 fused layers; d_out written only by layer 2 (deferred mean) ----
    const long long LTHREADS = (long long)ROWS * 8;
    layer_kernel<<<cdiv(LTHREADS, BT), BT, 0, stream>>>(
        perm, pA, pB, pC, cinfo, pm_all,
        c16A, p16A, g16, b16, c16B, p16B,
        cust_w, prod_w, c16B, p16B, out_c, out_p, 0);
    layer_kernel<<<cdiv(LTHREADS, BT), BT, 0, stream>>>(
        perm, pA, pB, pC, cinfo, pm_all,
        c16B, p16B, g16, b16, c16A, p16A,
        cust_w, prod_w, c16B, p16B, out_c, out_p, 1);
    layer_kernel<<<cdiv(LTHREADS, BT), BT, 0, stream>>>(
        perm, pA, pB, pC, cinfo, pm_all,
        c16A, p16A, g16, b16, c16B, p16B,           // s2 = A (gather source)
        cust_w, prod_w, c16B, p16B,                 // s0 = inputs, s1 = B
        out_c, out_p, 2);
}